// Round 20
// baseline (76.038 us; speedup 1.0000x reference)
//
#include <hip/hip_runtime.h>
#include <hip/hip_bf16.h>

#define IMG    512
#define KSZ    11
#define PANEL  16          // rows per H panel / V step
#define STRIP  64          // cols per block (4 waves x 16)
#define FS     20          // per-field stride in u32 = 20 pairs (5 groups of 4)
#define CS     84          // per-col stride u32 (4*FS + 4 pad; 84/4=21 odd -> full bank spread)
#define WRSZ   (16 * CS)   // per-wave ring size in u32 (1344)

typedef short bf16x8 __attribute__((ext_vector_type(8)));
typedef float f32x4  __attribute__((ext_vector_type(4)));
union S8 { bf16x8 v; ushort u16[8]; uint u32[4]; };

__device__ __forceinline__ uint cvtpk(float lo, float hi) {
    uint r;
    asm("v_cvt_pk_bf16_f32 %0, %1, %2" : "=v"(r) : "v"(lo), "v"(hi));
    return r;
}
__device__ __forceinline__ float2 pk_mul(float2 a, float2 b) {
    float2 d;
    asm("v_pk_mul_f32 %0, %1, %2" : "=v"(d) : "v"(a), "v"(b));
    return d;
}
__device__ __forceinline__ float2 pk_add(float2 a, float2 b) {
    float2 d;
    asm("v_pk_add_f32 %0, %1, %2" : "=v"(d) : "v"(a), "v"(b));
    return d;
}
__device__ __forceinline__ float2 pk_fma(float2 a, float2 b, float2 c) {
    float2 d;
    asm("v_pk_fma_f32 %0, %1, %2, %3" : "=v"(d) : "v"(a), "v"(b), "v"(c));
    return d;
}
__device__ __forceinline__ ushort f2bf(float f) {   // prologue-only
    union { __hip_bfloat16 h; ushort u; } c;
    c.h = __float2bfloat16(f);
    return c.u;
}

// MFMA 16x16x32 bf16 layouts (validated end-to-end R12-R19):
//   A: row=lane&15, k=8*(lane>>4)+i   B: col=lane&15, k=8*(lane>>4)+i
//   D: col=lane&15, row=4*(lane>>4)+reg
// R20: 4 FIELDS {s=x+y, d=x-y, P=s^2, M=d^2} replace 5 (identity:
//   2uxuy=(us^2-ud^2)/2, ux^2+uy^2=(us^2+ud^2)/2, 2sxy=((P-us^2)-(M-ud^2))/2,
//   sx+sy=((P-us^2)+(M-ud^2))/2) -> 8 MFMA, 8 ring writes, 4 ring reads.
// No row bounds checks: H(32) (rows 512..527, half 1) is 8 zero b64 writes,
// no loads; all other loads rows<512. Col spans 8-aligned -> lane fully
// in/out -> single colok branch.
// Ring/group algebra carried verbatim from R18 (passed, absmax 0):
//   20-pair ring (5 groups x 4), ring row = abs+8, ONE Toeplitz g[k-cj-3],
//   H b64 at group (2t+1+(q>>1))%5 offset 2(q&1); V b128 group (2(t-1)+q)%5,
//   order H(t) then V(t-1); same-wave lgkmcnt orders ds ops (R15).

__global__ __launch_bounds__(256)
void dssim_mfma_kernel(const float* __restrict__ x,
                       const float* __restrict__ y,
                       const float* __restrict__ kern,
                       float* __restrict__ out)
{
    __shared__ float  sgf[16];
    __shared__ ushort gext[64];
    __shared__ __align__(16) uint Wring[4 * WRSZ];   // 21504 B
    __shared__ float  wsum[4];

    const int tid = threadIdx.x;
    const int l   = tid & 63;
    const int wv  = tid >> 6;
    const int q   = l >> 4;
    const int cj  = l & 15;
    const int wb  = wv * WRSZ;

    if (tid < KSZ) {
        float s = 0.f;
        #pragma unroll
        for (int j = 0; j < KSZ; ++j) s += kern[tid * KSZ + j];
        sgf[tid] = s;   // k2d rows sum to g (sum(g)==1)
    }
    // zero group 0 (pairs 0..3 = ring rows 0..7 = abs -8..-1) of OWN ring:
    // 16 cols x 4 fields x 4 pairs = 256 u32
    for (int i = l; i < 256; i += 64) {
        const int col = i >> 4, r = i & 15, f = r >> 2, p = r & 3;
        Wring[wb + col * CS + f * FS + p] = 0u;
    }
    __syncthreads();
    if (tid < 64) {
        const int d = tid - 18;    // slot 18+d holds g[d]
        gext[tid] = (d >= 0 && d < KSZ) ? f2bf(sgf[d]) : (ushort)0;
    }
    __syncthreads();               // last barrier before epilogue

    // Single Toeplitz frag for BOTH passes: g[k-cj-3] -> slot 15+k-cj.
    S8 tg;
    #pragma unroll
    for (int ii = 0; ii < 8; ++ii)
        tg.u16[ii] = gext[15 + q * 8 + ii - cj];

    const int plane  = blockIdx.z;
    const int half   = blockIdx.y;
    const int cstrip = blockIdx.x * STRIP;
    const int base   = plane * (IMG * IMG);

    const int  cb    = cstrip - 8 + 16 * wv + 8 * q;   // multiple of 8
    const bool colok = (cb >= 0) && (cb + 8 <= IMG);   // span fully in/out
    const float* xl  = x + base + cb + cj * IMG;       // lane row-0 pointer
    const float* yl  = y + base + cb + cj * IMG;

    // half 0: t=0..16 all real H; V(s=t-1) t>=1   (s=0..15)
    // half 1: t=15..32, real H t<=31, H(32)=zero-write; V t>=17 (s=16..31)
    const int t0    = half ? 15 : 0;
    const int t1    = half ? 32 : 16;
    const int hreal = half ? 31 : 16;   // last real-H (and last load) panel
    const int vmin  = half ? 17 : 1;

    const f32x4 z0 = {0.f, 0.f, 0.f, 0.f};
    const float C1 = 1e-4f, C2 = 9e-4f;
    const float2 m1 = make_float2(-1.f, -1.f);
    float local = 0.f;                  // accumulates SSIM (not dssim)
    const int colbase = wb + cj * CS;

    int hg = (2 * t0 + 1 + (q >> 1)) % 5;          // H write group
    int vg = (2 * t0 - 2 + q + 10) % 5;            // V read group (s=t-1)
    const int ho = 2 * (q & 1);                    // H write offset in group

    f32x4 xa0, xb0, ya0, yb0, xa1, xb1, ya1, yb1;  // 2-deep load buffers

    auto load8 = [&](int t, f32x4& xa, f32x4& xb, f32x4& ya, f32x4& yb) {
        const float* px = xl + t * (PANEL * IMG);
        const float* py = yl + t * (PANEL * IMG);
        if (colok) {        // uniform-true in interior blocks -> else skipped
            xa = *(const f32x4*)px;  xb = *(const f32x4*)(px + 4);
            ya = *(const f32x4*)py;  yb = *(const f32x4*)(py + 4);
        } else {
            xa = z0; xb = z0; ya = z0; yb = z0;
        }
    };

    auto step = [&](int t, f32x4& xa, f32x4& xb, f32x4& ya, f32x4& yb) {
        const int hw = colbase + hg * 4 + ho;
        if (t <= hreal) {
            // ---- build 4 bf16 A-frags: s, d, P=s^2, M=d^2 ----
            S8 fs, fd, fP, fM;
            #pragma unroll
            for (int w = 0; w < 4; ++w) {
                const float2 xv = (w == 0) ? make_float2(xa[0], xa[1])
                                : (w == 1) ? make_float2(xa[2], xa[3])
                                : (w == 2) ? make_float2(xb[0], xb[1])
                                :            make_float2(xb[2], xb[3]);
                const float2 yv = (w == 0) ? make_float2(ya[0], ya[1])
                                : (w == 1) ? make_float2(ya[2], ya[3])
                                : (w == 2) ? make_float2(yb[0], yb[1])
                                :            make_float2(yb[2], yb[3]);
                const float2 sv = pk_add(xv, yv);
                const float2 dv = pk_fma(yv, m1, xv);   // x - y
                const float2 Pv = pk_mul(sv, sv);
                const float2 Mv = pk_mul(dv, dv);
                fs.u32[w] = cvtpk(sv.x, sv.y);
                fd.u32[w] = cvtpk(dv.x, dv.y);
                fP.u32[w] = cvtpk(Pv.x, Pv.y);
                fM.u32[w] = cvtpk(Mv.x, Mv.y);
            }

            // ---- refill this buffer for t+2 ----
            if (t + 2 <= hreal) load8(t + 2, xa, xb, ya, yb);

            // ---- H(t): 4 MFMAs -> ring, one b64 write each ----
            f32x4 d;
            uint2 w2;
            d = __builtin_amdgcn_mfma_f32_16x16x32_bf16(fs.v, tg.v, z0, 0, 0, 0);
            w2.x = cvtpk(d[0], d[1]);  w2.y = cvtpk(d[2], d[3]);
            *(uint2*)&Wring[hw + 0 * FS] = w2;
            d = __builtin_amdgcn_mfma_f32_16x16x32_bf16(fd.v, tg.v, z0, 0, 0, 0);
            w2.x = cvtpk(d[0], d[1]);  w2.y = cvtpk(d[2], d[3]);
            *(uint2*)&Wring[hw + 1 * FS] = w2;
            d = __builtin_amdgcn_mfma_f32_16x16x32_bf16(fP.v, tg.v, z0, 0, 0, 0);
            w2.x = cvtpk(d[0], d[1]);  w2.y = cvtpk(d[2], d[3]);
            *(uint2*)&Wring[hw + 2 * FS] = w2;
            d = __builtin_amdgcn_mfma_f32_16x16x32_bf16(fM.v, tg.v, z0, 0, 0, 0);
            w2.x = cvtpk(d[0], d[1]);  w2.y = cvtpk(d[2], d[3]);
            *(uint2*)&Wring[hw + 3 * FS] = w2;
        } else {
            // H(32), half 1 only: rows 512..527 are conv zero-padding
            const uint2 zz = {0u, 0u};
            #pragma unroll
            for (int f = 0; f < 4; ++f) *(uint2*)&Wring[hw + f * FS] = zz;
        }

        // ---- V(t-1) + SSIM (same-wave lgkmcnt orders ds ops) ----
        if (t >= vmin) {
            const int vr = colbase + vg * 4;
            f32x4 vf[4];
            #pragma unroll
            for (int f = 0; f < 4; ++f) {
                const uint4 bb = *(const uint4*)&Wring[vr + f * FS];   // b128
                S8 b;
                b.u32[0] = bb.x; b.u32[1] = bb.y; b.u32[2] = bb.z; b.u32[3] = bb.w;
                vf[f] = __builtin_amdgcn_mfma_f32_16x16x32_bf16(tg.v, b.v, z0, 0, 0, 0);
            }
            #pragma unroll
            for (int r = 0; r < 4; ++r) {
                const float us = vf[0][r], ud = vf[1][r];
                const float P  = vf[2][r], M  = vf[3][r];
                const float u  = us * us, v = ud * ud;
                const float a  = fmaf(0.5f, u - v, C1);   // 2 ux uy + C1
                const float b  = fmaf(0.5f, u + v, C1);   // ux^2+uy^2 + C1
                const float ps = P - u,  md = M - v;
                const float c  = fmaf(0.5f, ps - md, C2); // 2 sxy + C2
                const float e  = fmaf(0.5f, ps + md, C2); // sx+sy + C2
                local += __fdividef(a * c, fmaf(b, e, 1e-8f));
            }
        }

        hg += 2;  if (hg >= 5) hg -= 5;
        vg += 2;  if (vg >= 5) vg -= 5;
    };

    load8(t0,     xa0, xb0, ya0, yb0);
    load8(t0 + 1, xa1, xb1, ya1, yb1);

    for (int tt = t0; tt <= t1; tt += 2) {
        step(tt, xa0, xb0, ya0, yb0);
        if (tt + 1 <= t1) step(tt + 1, xa1, xb1, ya1, yb1);
    }

    // ---- block reduction; fold (1-ssim)/2 here: sum_px = 64x256 = 16384 ----
    #pragma unroll
    for (int o = 32; o > 0; o >>= 1) local += __shfl_down(local, o, 64);
    if (l == 0) wsum[wv] = local;
    __syncthreads();
    if (tid == 0) {
        const float ssimsum = wsum[0] + wsum[1] + wsum[2] + wsum[3];
        atomicAdd(out, (16384.f - ssimsum) * (0.5f / 25165824.f));
    }
}

extern "C" void kernel_launch(void* const* d_in, const int* in_sizes, int n_in,
                              void* d_out, int out_size, void* d_ws, size_t ws_size,
                              hipStream_t stream)
{
    const float* x    = (const float*)d_in[0];
    const float* y    = (const float*)d_in[1];
    const float* kern = (const float*)d_in[2];
    float* out = (float*)d_out;

    hipMemsetAsync(out, 0, sizeof(float), stream);

    dim3 grid(IMG / STRIP, 2, 32 * 3);   // 8 strips x 2 halves x 96 planes
    dssim_mfma_kernel<<<grid, 256, 0, stream>>>(x, y, kern, out);
}